// Round 9
// baseline (126.517 us; speedup 1.0000x reference)
//
#include <hip/hip_runtime.h>
#include <hip/hip_bf16.h>

#define NB 16
#define NQ 128
#define NK 512
#define DIN 256   // QS == KS == 256
#define NH 128
#define NDV 256

#define CSC 2.8853900817779268f   // 2*log2(e): tanh(x) = 1 - 2/(1 + 2^(CSC*x))

// Projection v9 (EXACT revert to R7's best; v10's d-split regressed and
// produced an intermittent 31.6ms pathological dispatch). v7 all-LDS core +
// XCD-aligned block mapping (blockIdx % 16 == b on both paths -> producer
// XCD == consumer XCD; EKT[b]+EQ[b] local-L2-hot for attn).
// Outputs EXPONENTIALS: EQ = 2^(CSC*qproj), EKT = 2^(CSC*kproj) transposed.
// K-path blocks fully beyond valid_len exit immediately (never read).
__global__ __launch_bounds__(256) void proj_both_kernel(
    const float* __restrict__ Q, const float* __restrict__ K,
    const float* __restrict__ Wq, const float* __restrict__ Wk,
    const int* __restrict__ vlen,
    float* __restrict__ EQ, float* __restrict__ EKT)
{
    __shared__ float Xl[32 * DIN];   // 32KB; reused as transpose tile for K path
    __shared__ float Wl[64 * NH];    // 32KB; d-chunk of W
    const int tid = threadIdx.x;
    int blk = blockIdx.x;
    const float* X; const float* W;
    int b, r0, isq;
    if (blk < 64) { isq = 1; b = blk & 15; r0 = (blk >> 4) * 32;   // XCD b%8
                    X = Q + ((size_t)b * NQ + r0) * DIN; W = Wq; }
    else { blk -= 64; isq = 0; b = blk & 15; r0 = (blk >> 4) * 32; // XCD b%8
           X = K + ((size_t)b * NK + r0) * DIN; W = Wk;
           int vl = vlen[b]; vl = vl < 1 ? 1 : (vl > NK ? NK : vl);
           if (r0 >= vl) return;     // block-uniform: masked-out key rows, never read
    }

    {   // stage 32 rows of X: 2048 float4, coalesced
        const float4* Xg = (const float4*)X;
        float4* Xs = (float4*)Xl;
        #pragma unroll
        for (int i = 0; i < 8; ++i) Xs[tid + 256 * i] = Xg[tid + 256 * i];
    }

    const int h4 = tid & 31;          // h = 4*h4
    const int rg = tid >> 5;          // rows rg*4 .. rg*4+3
    const float4* Wg = (const float4*)W;   // [256*128/4] float4; chunk c at c*2048
    float4* Ws4 = (float4*)Wl;

    float4 acc[4];
    #pragma unroll
    for (int r = 0; r < 4; ++r) { acc[r].x = 0.f; acc[r].y = 0.f; acc[r].z = 0.f; acc[r].w = 0.f; }

    // chunk 0: load to regs, write to LDS (first __syncthreads is inside loop)
    float4 pre[8];
    #pragma unroll
    for (int j = 0; j < 8; ++j) pre[j] = Wg[tid + 256 * j];
    #pragma unroll
    for (int j = 0; j < 8; ++j) Ws4[tid + 256 * j] = pre[j];

    for (int c = 0; c < 4; ++c) {     // 4 d-chunks of 64
        if (c < 3) {                  // issue next chunk's loads; latency hides under compute
            #pragma unroll
            for (int j = 0; j < 8; ++j) pre[j] = Wg[(c + 1) * 2048 + tid + 256 * j];
        }
        __syncthreads();              // Wl (and Xl on c==0) ready

        const float* Xc = &Xl[c * 64];
        #pragma unroll 4
        for (int dd = 0; dd < 64; dd += 4) {
            float4 w0 = *(const float4*)&Wl[(dd + 0) * NH + 4 * h4];
            float4 w1 = *(const float4*)&Wl[(dd + 1) * NH + 4 * h4];
            float4 w2 = *(const float4*)&Wl[(dd + 2) * NH + 4 * h4];
            float4 w3 = *(const float4*)&Wl[(dd + 3) * NH + 4 * h4];
            #pragma unroll
            for (int r = 0; r < 4; ++r) {
                float4 x = *(const float4*)&Xc[(rg * 4 + r) * DIN + dd];  // broadcast
                acc[r].x += x.x * w0.x + x.y * w1.x + x.z * w2.x + x.w * w3.x;
                acc[r].y += x.x * w0.y + x.y * w1.y + x.z * w2.y + x.w * w3.y;
                acc[r].z += x.x * w0.z + x.y * w1.z + x.z * w2.z + x.w * w3.z;
                acc[r].w += x.x * w0.w + x.y * w1.w + x.z * w2.w + x.w * w3.w;
            }
        }
        __syncthreads();              // all waves done reading Wl
        if (c < 3) {
            #pragma unroll
            for (int j = 0; j < 8; ++j) Ws4[tid + 256 * j] = pre[j];
        }
    }

    #pragma unroll
    for (int r = 0; r < 4; ++r) {    // scale then exponentiate: store 2^(CSC*proj)
        acc[r].x = __builtin_amdgcn_exp2f(CSC * acc[r].x);
        acc[r].y = __builtin_amdgcn_exp2f(CSC * acc[r].y);
        acc[r].z = __builtin_amdgcn_exp2f(CSC * acc[r].z);
        acc[r].w = __builtin_amdgcn_exp2f(CSC * acc[r].w);
    }

    if (isq) {
        #pragma unroll
        for (int r = 0; r < 4; ++r)
            *(float4*)&EQ[((size_t)b * NQ + r0 + rg * 4 + r) * NH + 4 * h4] = acc[r];
    } else {
        float* T = Xl;                // [128 h][36] padded (36*4B % 16 == 0)
        __syncthreads();
        #pragma unroll
        for (int r = 0; r < 4; ++r) {
            T[(4 * h4 + 0) * 36 + rg * 4 + r] = acc[r].x;
            T[(4 * h4 + 1) * 36 + rg * 4 + r] = acc[r].y;
            T[(4 * h4 + 2) * 36 + rg * 4 + r] = acc[r].z;
            T[(4 * h4 + 3) * 36 + rg * 4 + r] = acc[r].w;
        }
        __syncthreads();
        #pragma unroll
        for (int i = 0; i < 4; ++i) {
            const int idx = tid + 256 * i;        // 0..1023
            const int h = idx >> 3, c8 = idx & 7; // 8 float4 per h row
            float4 v = *(const float4*)&T[h * 36 + c8 * 4];
            *(float4*)&EKT[((size_t)b * NH + h) * NK + r0 + c8 * 4] = v;
        }
    }
}

// Fused scores + masked softmax + attn@V (v4): 8 q-rows per block.
// Per-block EKT read (256KB) and V read (up to 512KB) are INDEPENDENT of
// rows/block -> doubling rows to 8 (grid 512->256, b=blk&15 pinning kept)
// halves total EKT traffic (128->64MB), halves V traffic, halves score-loop
// VMEM instruction count, at the same total compute (2x FLOP per load).
// All 8 waves now do softmax (one row each) and the final store uses all
// 512 threads. LDS 52.5KB, VGPR<=128 (launch_bounds(512,2)) -> 2 blocks/CU.
// Score math unchanged (h-paired rcp): numerically identical per element.
__global__ __launch_bounds__(512, 2) void attn_fused_kernel(
    const float* __restrict__ EQ, const float* __restrict__ EKT,
    const float* __restrict__ wv, const int* __restrict__ vlen,
    const float* __restrict__ V, float* __restrict__ OUT)
{
    __shared__ float eq8[NH * 8];        // 4KB   [h][r] packed for ds_read_b128 x2
    __shared__ float wvl[NH];            // 0.5KB -2*wv
    __shared__ float sc8[NK * 8];        // 16KB  [k][row] scores -> attn
    __shared__ float part[4][8][NDV];    // 32KB  [k-quarter][row][d]
    const int tid = threadIdx.x;
    const int b  = blockIdx.x & 15;      // XCD-local batch
    const int q0 = (blockIdx.x >> 4) * 8;

    {   // stage q-exponentials transposed: eq8[h*8 + r] (1024 scalar loads)
        #pragma unroll
        for (int i = 0; i < 2; ++i) {
            const int idx = tid + 512 * i;
            const int h = idx >> 3, r = idx & 7;
            eq8[h * 8 + r] = EQ[((size_t)b * NQ + q0 + r) * NH + h];
        }
    }
    if (tid < NH) wvl[tid] = -2.0f * wv[tid];
    __syncthreads();

    int vl = vlen[b];
    vl = vl < 1 ? 1 : (vl > NK ? NK : vl);

    // ---- scores: score'(r,k) = sum_h wvl[h]/(1 + eq[r][h]*ek[h][k]),
    // h-paired: one rcp per two h, 8 rows per thread.
    {
        float4 aA = {0.f, 0.f, 0.f, 0.f};   // rows 0..3
        float4 aB = {0.f, 0.f, 0.f, 0.f};   // rows 4..7
        const bool vld = (tid < vl);
        if (vld) {
            const float* kb = EKT + (size_t)b * NH * NK + tid;
            #pragma unroll 4
            for (int h = 0; h < NH; h += 2) {
                float ek0 = kb[(size_t)h * NK];          // coalesced, local-L2-hot
                float ek1 = kb[(size_t)(h + 1) * NK];
                float4 ea0 = *(const float4*)&eq8[h * 8];          // rows 0-3
                float4 ea1 = *(const float4*)&eq8[h * 8 + 4];      // rows 4-7
                float4 eb0 = *(const float4*)&eq8[(h + 1) * 8];
                float4 eb1 = *(const float4*)&eq8[(h + 1) * 8 + 4];
                float w0 = wvl[h], w1 = wvl[h + 1];
                {   float y0 = __builtin_fmaf(ea0.x, ek0, 1.0f);
                    float y1 = __builtin_fmaf(eb0.x, ek1, 1.0f);
                    float n  = __builtin_fmaf(w0, y1, w1 * y0);
                    aA.x = __builtin_fmaf(n, __builtin_amdgcn_rcpf(y0 * y1), aA.x); }
                {   float y0 = __builtin_fmaf(ea0.y, ek0, 1.0f);
                    float y1 = __builtin_fmaf(eb0.y, ek1, 1.0f);
                    float n  = __builtin_fmaf(w0, y1, w1 * y0);
                    aA.y = __builtin_fmaf(n, __builtin_amdgcn_rcpf(y0 * y1), aA.y); }
                {   float y0 = __builtin_fmaf(ea0.z, ek0, 1.0f);
                    float y1 = __builtin_fmaf(eb0.z, ek1, 1.0f);
                    float n  = __builtin_fmaf(w0, y1, w1 * y0);
                    aA.z = __builtin_fmaf(n, __builtin_amdgcn_rcpf(y0 * y1), aA.z); }
                {   float y0 = __builtin_fmaf(ea0.w, ek0, 1.0f);
                    float y1 = __builtin_fmaf(eb0.w, ek1, 1.0f);
                    float n  = __builtin_fmaf(w0, y1, w1 * y0);
                    aA.w = __builtin_fmaf(n, __builtin_amdgcn_rcpf(y0 * y1), aA.w); }
                {   float y0 = __builtin_fmaf(ea1.x, ek0, 1.0f);
                    float y1 = __builtin_fmaf(eb1.x, ek1, 1.0f);
                    float n  = __builtin_fmaf(w0, y1, w1 * y0);
                    aB.x = __builtin_fmaf(n, __builtin_amdgcn_rcpf(y0 * y1), aB.x); }
                {   float y0 = __builtin_fmaf(ea1.y, ek0, 1.0f);
                    float y1 = __builtin_fmaf(eb1.y, ek1, 1.0f);
                    float n  = __builtin_fmaf(w0, y1, w1 * y0);
                    aB.y = __builtin_fmaf(n, __builtin_amdgcn_rcpf(y0 * y1), aB.y); }
                {   float y0 = __builtin_fmaf(ea1.z, ek0, 1.0f);
                    float y1 = __builtin_fmaf(eb1.z, ek1, 1.0f);
                    float n  = __builtin_fmaf(w0, y1, w1 * y0);
                    aB.z = __builtin_fmaf(n, __builtin_amdgcn_rcpf(y0 * y1), aB.z); }
                {   float y0 = __builtin_fmaf(ea1.w, ek0, 1.0f);
                    float y1 = __builtin_fmaf(eb1.w, ek1, 1.0f);
                    float n  = __builtin_fmaf(w0, y1, w1 * y0);
                    aB.w = __builtin_fmaf(n, __builtin_amdgcn_rcpf(y0 * y1), aB.w); }
            }
        }
        float4 svA, svB;
        svA.x = vld ? aA.x : -1e6f;  svA.y = vld ? aA.y : -1e6f;
        svA.z = vld ? aA.z : -1e6f;  svA.w = vld ? aA.w : -1e6f;
        svB.x = vld ? aB.x : -1e6f;  svB.y = vld ? aB.y : -1e6f;
        svB.z = vld ? aB.z : -1e6f;  svB.w = vld ? aB.w : -1e6f;
        *(float4*)&sc8[tid * 8]     = svA;   // packed [k][row]
        *(float4*)&sc8[tid * 8 + 4] = svB;
    }
    __syncthreads();

    // ---- masked softmax: wave w (0..7) owns row w
    const int w = tid >> 6, lane = tid & 63;
    {
        float vals[8];
        float m = -3.0e38f;
        #pragma unroll
        for (int i = 0; i < 8; ++i) { vals[i] = sc8[(lane + 64 * i) * 8 + w]; m = fmaxf(m, vals[i]); }
        #pragma unroll
        for (int off = 32; off; off >>= 1) m = fmaxf(m, __shfl_xor(m, off, 64));
        float s = 0.f;
        #pragma unroll
        for (int i = 0; i < 8; ++i) {
            vals[i] = __builtin_amdgcn_exp2f((vals[i] - m) * 1.4426950408889634f);
            s += vals[i];
        }
        #pragma unroll
        for (int off = 32; off; off >>= 1) s += __shfl_xor(s, off, 64);
        const float invs = 1.0f / s;   // s >= 1
        #pragma unroll
        for (int i = 0; i < 8; ++i) sc8[(lane + 64 * i) * 8 + w] = vals[i] * invs;
    }
    __syncthreads();

    // ---- out partials: wave w covers k in [w*64, w*64+64) for ALL 8 rows
    float4 o[8];
    #pragma unroll
    for (int r = 0; r < 8; ++r) { o[r].x = 0.f; o[r].y = 0.f; o[r].z = 0.f; o[r].w = 0.f; }
    {
        const int kb0 = w * 64;
        if (kb0 < vl) {                  // wave-uniform: skip all-zero-prob slices
            const int kn = (vl - kb0 < 64) ? (vl - kb0) : 64;  // clamp dead tail
            const float* vb = V + (size_t)b * NK * NDV + lane * 4;
            #pragma unroll 4
            for (int kk = 0; kk < kn; ++kk) {
                const int k = kb0 + kk;
                float4 v4 = *(const float4*)(vb + (size_t)k * NDV);   // 1KB/wave coalesced
                float4 pA = *(const float4*)&sc8[k * 8];              // broadcast b128
                float4 pB = *(const float4*)&sc8[k * 8 + 4];
                o[0].x += pA.x * v4.x; o[0].y += pA.x * v4.y; o[0].z += pA.x * v4.z; o[0].w += pA.x * v4.w;
                o[1].x += pA.y * v4.x; o[1].y += pA.y * v4.y; o[1].z += pA.y * v4.z; o[1].w += pA.y * v4.w;
                o[2].x += pA.z * v4.x; o[2].y += pA.z * v4.y; o[2].z += pA.z * v4.z; o[2].w += pA.z * v4.w;
                o[3].x += pA.w * v4.x; o[3].y += pA.w * v4.y; o[3].z += pA.w * v4.z; o[3].w += pA.w * v4.w;
                o[4].x += pB.x * v4.x; o[4].y += pB.x * v4.y; o[4].z += pB.x * v4.z; o[4].w += pB.x * v4.w;
                o[5].x += pB.y * v4.x; o[5].y += pB.y * v4.y; o[5].z += pB.y * v4.z; o[5].w += pB.y * v4.w;
                o[6].x += pB.z * v4.x; o[6].y += pB.z * v4.y; o[6].z += pB.z * v4.z; o[6].w += pB.z * v4.w;
                o[7].x += pB.w * v4.x; o[7].y += pB.w * v4.y; o[7].z += pB.w * v4.z; o[7].w += pB.w * v4.w;
            }
        }
    }
    // stage 1: waves 4-7 write partials
    if (w >= 4) {
        #pragma unroll
        for (int r = 0; r < 8; ++r) *(float4*)&part[w - 4][r][lane * 4] = o[r];
    }
    __syncthreads();
    // stage 2: waves 0-3 pair-combine and write
    if (w < 4) {
        #pragma unroll
        for (int r = 0; r < 8; ++r) {
            float4 t = *(const float4*)&part[w][r][lane * 4];
            o[r].x += t.x; o[r].y += t.y; o[r].z += t.z; o[r].w += t.w;
            *(float4*)&part[w][r][lane * 4] = o[r];
        }
    }
    __syncthreads();
    // stage 3: sum 4 k-quarter partials, store coalesced (all 512 threads)
    {
        const int r = tid >> 6, d4 = tid & 63;
        float4 s = {0.f, 0.f, 0.f, 0.f};
        #pragma unroll
        for (int p = 0; p < 4; ++p) {
            float4 q = *(const float4*)&part[p][r][d4 * 4];
            s.x += q.x; s.y += q.y; s.z += q.z; s.w += q.w;
        }
        *(float4*)&OUT[((size_t)b * NQ + q0 + r) * NDV + d4 * 4] = s;
    }
}

extern "C" void kernel_launch(void* const* d_in, const int* in_sizes, int n_in,
                              void* d_out, int out_size, void* d_ws, size_t ws_size,
                              hipStream_t stream) {
    const float* queries = (const float*)d_in[0];  // [16,128,256] f32
    const float* keys    = (const float*)d_in[1];  // [16,512,256] f32
    const float* values  = (const float*)d_in[2];  // [16,512,256] f32
    const int*   vlen    = (const int*)d_in[3];    // [16] int32
    const float* Wq      = (const float*)d_in[4];  // [256,128] f32
    const float* Wk      = (const float*)d_in[5];  // [256,128] f32
    const float* wv      = (const float*)d_in[6];  // [128] f32
    float* out           = (float*)d_out;          // [16,128,256] f32

    float* eq  = (float*)d_ws;                     // EQ  [16][128][128] = 1MB (2^(CSC*qproj))
    float* ekt = eq + (size_t)NB * NQ * NH;        // EKT [16][128][512] = 4MB (2^(CSC*kproj), transposed)

    proj_both_kernel<<<64 + 256, 256, 0, stream>>>(queries, keys, Wq, Wk, vlen, eq, ekt);
    attn_fused_kernel<<<NB * 16, 512, 0, stream>>>(eq, ekt, wv, vlen, values, out);
}

// Round 10
// 121.452 us; speedup vs baseline: 1.0417x; 1.0417x over previous
//
#include <hip/hip_runtime.h>
#include <hip/hip_bf16.h>

#define NB 16
#define NQ 128
#define NK 512
#define DIN 256   // QS == KS == 256
#define NH 128
#define NDV 256

#define CSC 2.8853900817779268f   // 2*log2(e): tanh(x) = 1 - 2/(1 + 2^(CSC*x))

// Projection v9 (session best, R7): v7 all-LDS core + XCD-aligned block
// mapping (blockIdx % 16 == b on both paths -> producer XCD == consumer
// XCD; EKT[b]+EQ[b] local-L2-hot for attn within the iteration).
// Outputs EXPONENTIALS: EQ = 2^(CSC*qproj), EKT = 2^(CSC*kproj) transposed;
// the score kernel then needs 0.5 trans ops per (q,k,h) via h-pairing.
// K-path blocks fully beyond valid_len exit immediately (never read).
// History: v8 (16-row tiles) regressed (LDS-bound balance), v10 (d-split)
// regressed + intermittent 31ms pathological dispatch. v7/v9 balance:
// 64 fma vs 8 LDS-reads per dd-group, compute-bound per thread.
__global__ __launch_bounds__(256) void proj_both_kernel(
    const float* __restrict__ Q, const float* __restrict__ K,
    const float* __restrict__ Wq, const float* __restrict__ Wk,
    const int* __restrict__ vlen,
    float* __restrict__ EQ, float* __restrict__ EKT)
{
    __shared__ float Xl[32 * DIN];   // 32KB; reused as transpose tile for K path
    __shared__ float Wl[64 * NH];    // 32KB; d-chunk of W
    const int tid = threadIdx.x;
    int blk = blockIdx.x;
    const float* X; const float* W;
    int b, r0, isq;
    if (blk < 64) { isq = 1; b = blk & 15; r0 = (blk >> 4) * 32;   // XCD b%8
                    X = Q + ((size_t)b * NQ + r0) * DIN; W = Wq; }
    else { blk -= 64; isq = 0; b = blk & 15; r0 = (blk >> 4) * 32; // XCD b%8
           X = K + ((size_t)b * NK + r0) * DIN; W = Wk;
           int vl = vlen[b]; vl = vl < 1 ? 1 : (vl > NK ? NK : vl);
           if (r0 >= vl) return;     // block-uniform: masked-out key rows, never read
    }

    {   // stage 32 rows of X: 2048 float4, coalesced
        const float4* Xg = (const float4*)X;
        float4* Xs = (float4*)Xl;
        #pragma unroll
        for (int i = 0; i < 8; ++i) Xs[tid + 256 * i] = Xg[tid + 256 * i];
    }

    const int h4 = tid & 31;          // h = 4*h4
    const int rg = tid >> 5;          // rows rg*4 .. rg*4+3
    const float4* Wg = (const float4*)W;   // [256*128/4] float4; chunk c at c*2048
    float4* Ws4 = (float4*)Wl;

    float4 acc[4];
    #pragma unroll
    for (int r = 0; r < 4; ++r) { acc[r].x = 0.f; acc[r].y = 0.f; acc[r].z = 0.f; acc[r].w = 0.f; }

    // chunk 0: load to regs, write to LDS (first __syncthreads is inside loop)
    float4 pre[8];
    #pragma unroll
    for (int j = 0; j < 8; ++j) pre[j] = Wg[tid + 256 * j];
    #pragma unroll
    for (int j = 0; j < 8; ++j) Ws4[tid + 256 * j] = pre[j];

    for (int c = 0; c < 4; ++c) {     // 4 d-chunks of 64
        if (c < 3) {                  // issue next chunk's loads; latency hides under compute
            #pragma unroll
            for (int j = 0; j < 8; ++j) pre[j] = Wg[(c + 1) * 2048 + tid + 256 * j];
        }
        __syncthreads();              // Wl (and Xl on c==0) ready

        const float* Xc = &Xl[c * 64];
        #pragma unroll 4
        for (int dd = 0; dd < 64; dd += 4) {
            float4 w0 = *(const float4*)&Wl[(dd + 0) * NH + 4 * h4];
            float4 w1 = *(const float4*)&Wl[(dd + 1) * NH + 4 * h4];
            float4 w2 = *(const float4*)&Wl[(dd + 2) * NH + 4 * h4];
            float4 w3 = *(const float4*)&Wl[(dd + 3) * NH + 4 * h4];
            #pragma unroll
            for (int r = 0; r < 4; ++r) {
                float4 x = *(const float4*)&Xc[(rg * 4 + r) * DIN + dd];  // broadcast
                acc[r].x += x.x * w0.x + x.y * w1.x + x.z * w2.x + x.w * w3.x;
                acc[r].y += x.x * w0.y + x.y * w1.y + x.z * w2.y + x.w * w3.y;
                acc[r].z += x.x * w0.z + x.y * w1.z + x.z * w2.z + x.w * w3.z;
                acc[r].w += x.x * w0.w + x.y * w1.w + x.z * w2.w + x.w * w3.w;
            }
        }
        __syncthreads();              // all waves done reading Wl
        if (c < 3) {
            #pragma unroll
            for (int j = 0; j < 8; ++j) Ws4[tid + 256 * j] = pre[j];
        }
    }

    #pragma unroll
    for (int r = 0; r < 4; ++r) {    // scale then exponentiate: store 2^(CSC*proj)
        acc[r].x = __builtin_amdgcn_exp2f(CSC * acc[r].x);
        acc[r].y = __builtin_amdgcn_exp2f(CSC * acc[r].y);
        acc[r].z = __builtin_amdgcn_exp2f(CSC * acc[r].z);
        acc[r].w = __builtin_amdgcn_exp2f(CSC * acc[r].w);
    }

    if (isq) {
        #pragma unroll
        for (int r = 0; r < 4; ++r)
            *(float4*)&EQ[((size_t)b * NQ + r0 + rg * 4 + r) * NH + 4 * h4] = acc[r];
    } else {
        float* T = Xl;                // [128 h][36] padded (36*4B % 16 == 0)
        __syncthreads();
        #pragma unroll
        for (int r = 0; r < 4; ++r) {
            T[(4 * h4 + 0) * 36 + rg * 4 + r] = acc[r].x;
            T[(4 * h4 + 1) * 36 + rg * 4 + r] = acc[r].y;
            T[(4 * h4 + 2) * 36 + rg * 4 + r] = acc[r].z;
            T[(4 * h4 + 3) * 36 + rg * 4 + r] = acc[r].w;
        }
        __syncthreads();
        #pragma unroll
        for (int i = 0; i < 4; ++i) {
            const int idx = tid + 256 * i;        // 0..1023
            const int h = idx >> 3, c8 = idx & 7; // 8 float4 per h row
            float4 v = *(const float4*)&T[h * 36 + c8 * 4];
            *(float4*)&EKT[((size_t)b * NH + h) * NK + r0 + c8 * 4] = v;
        }
    }
}

// Fused scores + masked softmax + attn@V (v3, session best, R7).
// Block = (b, 4 q rows), 512 thr = 8 waves, grid 512; b = blk&15 -> batch
// pinned to XCD b%8 (EKT[b]+EQ[b]+V[b] local-L2; 32 blocks/batch keep the
// whole XCD busy -- R9's 8-row variant halved that and regressed).
// __launch_bounds__(512,2): VGPR cap 128 so the score loop's L2 loads
// pipeline. h-paired rcp scores (0.5 trans/elem):
//   w0/(1+x0)+w1/(1+x1) = (w0*y1+w1*y0)*rcp(y0*y1), y=1+x
// sc4[k][4] packing (attn@V reads 4 rows per ds_read_b128), clamped V-loop.
__global__ __launch_bounds__(512, 2) void attn_fused_kernel(
    const float* __restrict__ EQ, const float* __restrict__ EKT,
    const float* __restrict__ wv, const int* __restrict__ vlen,
    const float* __restrict__ V, float* __restrict__ OUT)
{
    __shared__ float eq4[NH * 4];        // 2KB   [h][r] packed for ds_read_b128
    __shared__ float wvl[NH];            // 0.5KB -2*wv
    __shared__ float sc4[NK * 4];        // 8KB   [k][row] scores -> attn
    __shared__ float part[4][4][NDV];    // 16KB  [k-quarter][row][d]
    const int tid = threadIdx.x;
    const int b  = blockIdx.x & 15;      // XCD-local batch
    const int q0 = (blockIdx.x >> 4) * 4;

    {   // stage q-exponentials transposed: eq4[h*4 + r]
        const int r = tid >> 7, h = tid & 127;
        eq4[h * 4 + r] = EQ[((size_t)b * NQ + q0 + r) * NH + h];
    }
    if (tid < NH) wvl[tid] = -2.0f * wv[tid];
    __syncthreads();

    int vl = vlen[b];
    vl = vl < 1 ? 1 : (vl > NK ? NK : vl);

    // ---- scores: score'(r,k) = sum_h wvl[h]/(1 + eq[r][h]*ek[h][k]),
    // h-paired: one rcp per two h. (true score minus sum(wv): softmax-
    // invariant row shift)
    {
        float a0 = 0.f, a1 = 0.f, a2 = 0.f, a3 = 0.f;
        const bool vld = (tid < vl);
        if (vld) {
            const float* kb = EKT + (size_t)b * NH * NK + tid;
            #pragma unroll 8
            for (int h = 0; h < NH; h += 2) {
                float ek0 = kb[(size_t)h * NK];          // coalesced, local-L2-hot
                float ek1 = kb[(size_t)(h + 1) * NK];
                float4 ea = *(const float4*)&eq4[h * 4];       // LDS broadcast b128
                float4 eb = *(const float4*)&eq4[(h + 1) * 4];
                float w0 = wvl[h], w1 = wvl[h + 1];
                {   // row 0
                    float y0 = __builtin_fmaf(ea.x, ek0, 1.0f);
                    float y1 = __builtin_fmaf(eb.x, ek1, 1.0f);
                    float n  = __builtin_fmaf(w0, y1, w1 * y0);
                    a0 = __builtin_fmaf(n, __builtin_amdgcn_rcpf(y0 * y1), a0);
                }
                {   // row 1
                    float y0 = __builtin_fmaf(ea.y, ek0, 1.0f);
                    float y1 = __builtin_fmaf(eb.y, ek1, 1.0f);
                    float n  = __builtin_fmaf(w0, y1, w1 * y0);
                    a1 = __builtin_fmaf(n, __builtin_amdgcn_rcpf(y0 * y1), a1);
                }
                {   // row 2
                    float y0 = __builtin_fmaf(ea.z, ek0, 1.0f);
                    float y1 = __builtin_fmaf(eb.z, ek1, 1.0f);
                    float n  = __builtin_fmaf(w0, y1, w1 * y0);
                    a2 = __builtin_fmaf(n, __builtin_amdgcn_rcpf(y0 * y1), a2);
                }
                {   // row 3
                    float y0 = __builtin_fmaf(ea.w, ek0, 1.0f);
                    float y1 = __builtin_fmaf(eb.w, ek1, 1.0f);
                    float n  = __builtin_fmaf(w0, y1, w1 * y0);
                    a3 = __builtin_fmaf(n, __builtin_amdgcn_rcpf(y0 * y1), a3);
                }
            }
        }
        float4 sv;
        sv.x = vld ? a0 : -1e6f;
        sv.y = vld ? a1 : -1e6f;
        sv.z = vld ? a2 : -1e6f;
        sv.w = vld ? a3 : -1e6f;
        *(float4*)&sc4[tid * 4] = sv;    // packed [k][row]
    }
    __syncthreads();

    // ---- masked softmax: wave w (0..3) owns row w (strided sc4 access:
    // 8-way bank conflict on 8 reads + 8 writes - negligible phase)
    const int w = tid >> 6, lane = tid & 63;
    if (w < 4) {
        float vals[8];
        float m = -3.0e38f;
        #pragma unroll
        for (int i = 0; i < 8; ++i) { vals[i] = sc4[(lane + 64 * i) * 4 + w]; m = fmaxf(m, vals[i]); }
        #pragma unroll
        for (int off = 32; off; off >>= 1) m = fmaxf(m, __shfl_xor(m, off, 64));
        float s = 0.f;
        #pragma unroll
        for (int i = 0; i < 8; ++i) {
            vals[i] = __builtin_amdgcn_exp2f((vals[i] - m) * 1.4426950408889634f);
            s += vals[i];
        }
        #pragma unroll
        for (int off = 32; off; off >>= 1) s += __shfl_xor(s, off, 64);
        const float invs = 1.0f / s;   // s >= 1
        #pragma unroll
        for (int i = 0; i < 8; ++i) sc4[(lane + 64 * i) * 4 + w] = vals[i] * invs;
    }
    __syncthreads();

    // ---- out partials: wave w covers k in [w*64, w*64+64) for ALL 4 rows
    float4 o[4];
    #pragma unroll
    for (int r = 0; r < 4; ++r) { o[r].x = 0.f; o[r].y = 0.f; o[r].z = 0.f; o[r].w = 0.f; }
    {
        const int kb0 = w * 64;
        if (kb0 < vl) {                  // wave-uniform: skip all-zero-prob slices
            const int kn = (vl - kb0 < 64) ? (vl - kb0) : 64;  // clamp dead tail
            const float* vb = V + (size_t)b * NK * NDV + lane * 4;
            #pragma unroll 8
            for (int kk = 0; kk < kn; ++kk) {
                const int k = kb0 + kk;
                float4 v4 = *(const float4*)(vb + (size_t)k * NDV);   // 1KB/wave coalesced
                float4 p  = *(const float4*)&sc4[k * 4];              // broadcast b128
                o[0].x += p.x * v4.x; o[0].y += p.x * v4.y; o[0].z += p.x * v4.z; o[0].w += p.x * v4.w;
                o[1].x += p.y * v4.x; o[1].y += p.y * v4.y; o[1].z += p.y * v4.z; o[1].w += p.y * v4.w;
                o[2].x += p.z * v4.x; o[2].y += p.z * v4.y; o[2].z += p.z * v4.z; o[2].w += p.z * v4.w;
                o[3].x += p.w * v4.x; o[3].y += p.w * v4.y; o[3].z += p.w * v4.z; o[3].w += p.w * v4.w;
            }
        }
    }
    // stage 1: waves 4-7 write partials
    if (w >= 4) {
        #pragma unroll
        for (int r = 0; r < 4; ++r) *(float4*)&part[w - 4][r][lane * 4] = o[r];
    }
    __syncthreads();
    // stage 2: waves 0-3 pair-combine and write
    if (w < 4) {
        #pragma unroll
        for (int r = 0; r < 4; ++r) {
            float4 t = *(const float4*)&part[w][r][lane * 4];
            o[r].x += t.x; o[r].y += t.y; o[r].z += t.z; o[r].w += t.w;
            *(float4*)&part[w][r][lane * 4] = o[r];
        }
    }
    __syncthreads();
    // stage 3: sum 4 k-quarter partials, store coalesced
    if (tid < 256) {
        const int r = tid >> 6, d4 = tid & 63;
        float4 s = {0.f, 0.f, 0.f, 0.f};
        #pragma unroll
        for (int p = 0; p < 4; ++p) {
            float4 q = *(const float4*)&part[p][r][d4 * 4];
            s.x += q.x; s.y += q.y; s.z += q.z; s.w += q.w;
        }
        *(float4*)&OUT[((size_t)b * NQ + q0 + r) * NDV + d4 * 4] = s;
    }
}

extern "C" void kernel_launch(void* const* d_in, const int* in_sizes, int n_in,
                              void* d_out, int out_size, void* d_ws, size_t ws_size,
                              hipStream_t stream) {
    const float* queries = (const float*)d_in[0];  // [16,128,256] f32
    const float* keys    = (const float*)d_in[1];  // [16,512,256] f32
    const float* values  = (const float*)d_in[2];  // [16,512,256] f32
    const int*   vlen    = (const int*)d_in[3];    // [16] int32
    const float* Wq      = (const float*)d_in[4];  // [256,128] f32
    const float* Wk      = (const float*)d_in[5];  // [256,128] f32
    const float* wv      = (const float*)d_in[6];  // [128] f32
    float* out           = (float*)d_out;          // [16,128,256] f32

    float* eq  = (float*)d_ws;                     // EQ  [16][128][128] = 1MB (2^(CSC*qproj))
    float* ekt = eq + (size_t)NB * NQ * NH;        // EKT [16][128][512] = 4MB (2^(CSC*kproj), transposed)

    proj_both_kernel<<<64 + 256, 256, 0, stream>>>(queries, keys, Wq, Wk, vlen, eq, ekt);
    attn_fused_kernel<<<NB * 32, 512, 0, stream>>>(eq, ekt, wv, vlen, values, out);
}